// Round 5
// baseline (167.796 us; speedup 1.0000x reference)
//
#include <hip/hip_runtime.h>

// OESNN_SEPhIA_MultiTiled2: 32-step recurrent SNN, B=8192.
// R5: ONE WAVE PER BATCH ELEMENT. R1-R4 were all stalled ~70% on per-lane
// weight refetch (L1/LDS/scratch) because the register allocator refuses to
// hold ~90 weights/lane (VGPR capped at 92-120 regardless of launch bounds /
// waves_per_eu / asm pins -> it spilled). Fix: shrink per-lane weights to 18
// floats so residency is natural.
//   lanes 0..35 : layer-0 channel c=lane/2, parity par=lane&1 (even/odd col),
//                 18 W0 weights, one ascending-w fma chain; shfl_xor(1) gives
//                 se-so on even lanes.
//   lanes 36..51: layer-1 column col=lane-36, 18 W1 weights; pw values
//                 broadcast with compile-time-lane __shfl (v_readlane).
//   lanes 52..63: idle (clamped indices, results never stored).
// 8192 waves (~4/SIMD resident) for latency hiding; zero in-loop weight
// traffic; no LDS. Per-value numerics op-for-op identical to passing R1-R4.

namespace {
constexpr int Tn = 32;
constexpr int Bn = 8192;
constexpr int O_PW = 0;                       // spks0 (= pw0) [T,B,18]
constexpr int O_S1 = Tn * Bn * 18;            // spks1 [T,B,8]
constexpr int O_M0 = O_S1 + Tn * Bn * 8;      // mems0 [T,B,18]
constexpr int O_M1 = O_M0 + Tn * Bn * 18;     // mems1 [T,B,8]
}

__global__ __launch_bounds__(256, 4)
void oesnn_kernel(const float* __restrict__ x_in,
                  const float* __restrict__ W0g,   // [2,18,18*2]
                  const float* __restrict__ d0g,   // [2,9]
                  const float* __restrict__ W1g,   // [1,18,16]
                  const float* __restrict__ d1g,   // [1,8]
                  const float* __restrict__ peakg, // [36]
                  float* __restrict__ out)
{
    const int lane = threadIdx.x & 63;
    const int wv   = threadIdx.x >> 6;
    const int b    = blockIdx.x * 4 + wv;     // one wave = one batch element

    const bool isL0 = lane < 36;
    const int  par  = lane & 1;
    const int  c0i  = isL0 ? (lane >> 1) : 0; // layer-0 channel (clamped)
    const int  tl   = c0i / 9;
    const int  jc   = c0i - 9 * tl;
    const bool isL1 = (lane >= 36) && (lane < 52);
    const int  col  = isL1 ? (lane - 36) : 0; // layer-1 column (clamped)
    const int  o1   = col >> 1;               // layer-1 output channel

    // ---- 18 weights per lane, role-selected; loaded once ----
    float wreg[18];
    #pragma unroll
    for (int w = 0; w < 18; ++w)
        wreg[w] = isL0 ? W0g[(tl * 18 + w) * 18 + 2 * jc + par]
                       : W1g[w * 16 + col];
    #pragma unroll
    for (int w = 0; w < 18; ++w) { asm volatile("" : "+v"(wreg[w])); }

    const float dd0 = d0g[c0i];
    const float dd1 = d1g[o1];

    // pw0 two-value table per channel (reference's complex path, as in R1-R4)
    float pon, poff;
    {
        const int   c     = c0i;
        const float wl    = 1550.0f + 0.8f * (float)c;
        const float halfw = 0.5f * (wl * 1e3f / 15000.0f);
        const float amp   = sqrtf((exp10f(peakg[c] / 10.0f) / 1000.0f) * 1e6f);
        const float lr0   = 0.1f * amp;
        const float a0    = sqrtf(lr0 * lr0);
        poff = a0 * a0;
        const float delta = -250.0f / halfw;
        const float den   = fmaf(delta, delta, 1.0f);
        const float qr    = fmaf(delta, delta, 0.1f) / den;
        const float qi    = (delta - 0.1f * delta) / den;
        const float lr = qr * amp, li = qi * amp;
        const float a  = sqrtf(fmaf(lr, lr, li * li));
        pon = a * a;
    }

    // ---- state & pointers ----
    float mem0 = 0.f, mem1 = 0.f;
    const float* xp = x_in + (size_t)b * 36 + tl * 18;
    float* opw = out + O_PW + (size_t)b * 18 + c0i;
    float* om0 = out + O_M0 + (size_t)b * 18 + c0i;
    float* os1 = out + O_S1 + (size_t)b * 8 + o1;
    float* om1 = out + O_M1 + (size_t)b * 8 + o1;

    // prefetch t=0 (this tile's 18 x floats = 9x float2)
    float2 xv[9];
    #pragma unroll
    for (int k = 0; k < 9; ++k) xv[k] = *(const float2*)(xp + 2 * k);

    #pragma unroll 1
    for (int t = 0; t < Tn; ++t) {
        // ---- layer-0 dot: this lane's column-parity, ascending w ----
        // px = x * 1e-4 (separate rounded mul, as in reference), then fma.
        float acc = 0.f;
        #pragma unroll
        for (int k = 0; k < 9; ++k) {
            acc = fmaf(xv[k].x * 1e-4f, wreg[2 * k],     acc);
            acc = fmaf(xv[k].y * 1e-4f, wreg[2 * k + 1], acc);
        }

        // xv now free: prefetch next timestep (lands during the rest of iter)
        xp += Bn * 36;
        if (t < Tn - 1) {
            #pragma unroll
            for (int k = 0; k < 9; ++k) xv[k] = *(const float2*)(xp + 2 * k);
        }

        // ---- balanced PD + LIF + MRR power (valid on even L0 lanes) ----
        const float accp = __shfl_xor(acc, 1, 64);       // partner parity
        const float cc0  = (acc - accp) * dd0;           // se - so on even
        const float m2A  = (mem0 > 0.55f) ? 0.0f : fmaf(0.95f, mem0, cc0);
        mem0 = m2A;
        const float pw   = (m2A > 0.55f) ? pon : poff;
        if (isL0 && !par) {
            opw[0] = pw;                                 // 18 consecutive dwords
            om0[0] = m2A;
        }

        // ---- layer 1: broadcast pw from lane 2c, ascending-w chain ----
        float i1 = 0.f;
        #pragma unroll
        for (int c = 0; c < 18; ++c) {
            const float pv = __shfl(pw, 2 * c, 64);      // compile-time lane
            i1 = fmaf(pv, wreg[c], i1);
        }
        const float i1p = __shfl_xor(i1, 1, 64);         // partner column
        const float cc1 = (i1 - i1p) * dd1;              // even col - odd col
        const float m2B = (mem1 > 0.25f) ? 0.0f : fmaf(0.95f, mem1, cc1);
        mem1 = m2B;
        if (isL1 && !par) {
            os1[0] = (m2B > 0.25f) ? 1.0f : 0.0f;        // 8 consecutive dwords
            om1[0] = m2B;
        }

        opw += Bn * 18; om0 += Bn * 18;
        os1 += Bn * 8;  om1 += Bn * 8;
    }
}

extern "C" void kernel_launch(void* const* d_in, const int* in_sizes, int n_in,
                              void* d_out, int out_size, void* d_ws, size_t ws_size,
                              hipStream_t stream) {
    (void)in_sizes; (void)n_in; (void)out_size; (void)d_ws; (void)ws_size;
    const float* x  = (const float*)d_in[0];
    const float* W0 = (const float*)d_in[1];
    const float* d0 = (const float*)d_in[2];
    const float* W1 = (const float*)d_in[3];
    const float* d1 = (const float*)d_in[4];
    const float* pk = (const float*)d_in[5];
    float* out = (float*)d_out;

    dim3 grid(Bn / 4), block(256);               // one wave per batch element
    hipLaunchKernelGGL(oesnn_kernel, grid, block, 0, stream,
                       x, W0, d0, W1, d1, pk, out);
}

// Round 6
// 127.301 us; speedup vs baseline: 1.3181x; 1.3181x over previous
//
#include <hip/hip_runtime.h>

// OESNN_SEPhIA_MultiTiled2: 32-step recurrent SNN, B=8192.
// R6: 32 lanes per batch element (2 batches/wave, 4096 waves = 4/SIMD).
//   lane l5=lane&31: l5<18 -> layer-0 channel c=l5, holds BOTH parities
//   (36 W0 weights, se/so chains on one lane -> no shuffle for balanced PD).
//   All lanes: layer-1 column col=l5&15 (18 W1 weights); the 18 pw values
//   are broadcast with ds_swizzle (BitMode or-mask = source lane) -- no LDS,
//   no address VGPRs. Outputs for layer 1 on even lanes < 16.
// t-loop #pragma unroll 2: consecutive iterations' store-data become distinct
// SSA values so the allocator renames registers instead of draining stores
// (the hypothesized ~2.5k-cyc/iter store-source WAR stall seen in R1-R5).
// 32-bit voffset addressing throughout. Numerics op-for-op identical to the
// passing R1-R5 kernels.

namespace {
constexpr int Tn = 32;
constexpr int Bn = 8192;
constexpr unsigned O_PW = 0;                        // spks0 (= pw0) [T,B,18]
constexpr unsigned O_S1 = Tn * Bn * 18;             // spks1 [T,B,8]
constexpr unsigned O_M0 = O_S1 + Tn * Bn * 8;       // mems0 [T,B,18]
constexpr unsigned O_M1 = O_M0 + Tn * Bn * 18;      // mems1 [T,B,8]
}

template <int IMM>
__device__ __forceinline__ float swzf(float v) {
    return __int_as_float(__builtin_amdgcn_ds_swizzle(__float_as_int(v), IMM));
}

__global__ __launch_bounds__(256, 4)
void oesnn_kernel(const float* __restrict__ x_in,
                  const float* __restrict__ W0g,   // [2,18,18*2]
                  const float* __restrict__ d0g,   // [2,9]
                  const float* __restrict__ W1g,   // [1,18,16]
                  const float* __restrict__ d1g,   // [1,8]
                  const float* __restrict__ peakg, // [36]
                  float* __restrict__ out)
{
    const int wv   = threadIdx.x >> 6;          // wave in block (0..3)
    const int lane = threadIdx.x & 63;
    const int half = lane >> 5;                  // batch group in wave
    const int l5   = lane & 31;                  // lane in group
    const int b    = blockIdx.x * 8 + wv * 2 + half;

    const int  c    = (l5 < 18) ? l5 : 17;       // layer-0 channel (clamped)
    const int  tl   = c / 9;                     // tile
    const int  jc   = c - 9 * tl;
    const int  col  = l5 & 15;                   // layer-1 column
    const int  o1   = col >> 1;                  // layer-1 output channel
    const bool isL0  = l5 < 18;
    const bool isOut1 = (l5 < 16) && !(l5 & 1);

    // ---- weights: 36 (L0 e/o) + 18 (L1) floats per lane, loaded once ----
    float w0e[18], w0o[18];
    #pragma unroll
    for (int w = 0; w < 18; ++w) {
        const float2 p = *(const float2*)(W0g + (tl * 18 + w) * 18 + 2 * jc);
        w0e[w] = p.x;
        w0o[w] = p.y;
    }
    float w1[18];
    #pragma unroll
    for (int w = 0; w < 18; ++w)
        w1[w] = W1g[w * 16 + col];

    const float dd0 = d0g[c];
    const float dd1 = d1g[o1];

    // pw0 two-value table per channel (reference's complex path, as R1-R5)
    float pon, poff;
    {
        const float wl    = 1550.0f + 0.8f * (float)c;
        const float halfw = 0.5f * (wl * 1e3f / 15000.0f);
        const float amp   = sqrtf((exp10f(peakg[c] / 10.0f) / 1000.0f) * 1e6f);
        const float lr0   = 0.1f * amp;
        const float a0    = sqrtf(lr0 * lr0);
        poff = a0 * a0;
        const float delta = -250.0f / halfw;
        const float den   = fmaf(delta, delta, 1.0f);
        const float qr    = fmaf(delta, delta, 0.1f) / den;
        const float qi    = (delta - 0.1f * delta) / den;
        const float lr = qr * amp, li = qi * amp;
        const float a  = sqrtf(fmaf(lr, lr, li * li));
        pon = a * a;
    }

    // ---- state & 32-bit element offsets ----
    float mem0 = 0.f, mem1 = 0.f;
    unsigned xoff  = (unsigned)b * 36 + (unsigned)tl * 18;
    unsigned opw_i = O_PW + (unsigned)b * 18 + (unsigned)c;
    unsigned om0_i = O_M0 + (unsigned)b * 18 + (unsigned)c;
    unsigned os1_i = O_S1 + (unsigned)b * 8 + (unsigned)o1;
    unsigned om1_i = O_M1 + (unsigned)b * 8 + (unsigned)o1;

    // prefetch t=0 (this tile's 18 floats = 9x float2, 8B aligned)
    float2 xv[9];
    {
        const float2* xp2 = (const float2*)(x_in + xoff);
        #pragma unroll
        for (int k = 0; k < 9; ++k) xv[k] = xp2[k];
    }

    #pragma unroll 2
    for (int t = 0; t < Tn; ++t) {
        // ---- layer 0: px = x*1e-4, se/so ascending-w fma chains ----
        float se = 0.f, so = 0.f;
        #pragma unroll
        for (int k = 0; k < 9; ++k) {
            const float p0 = xv[k].x * 1e-4f;
            const float p1 = xv[k].y * 1e-4f;
            se = fmaf(p0, w0e[2 * k],     se);
            so = fmaf(p0, w0o[2 * k],     so);
            se = fmaf(p1, w0e[2 * k + 1], se);
            so = fmaf(p1, w0o[2 * k + 1], so);
        }

        // xv consumed: prefetch next timestep before any stores issue
        xoff += Bn * 36;
        if (t < Tn - 1) {
            const float2* xp2 = (const float2*)(x_in + xoff);
            #pragma unroll
            for (int k = 0; k < 9; ++k) xv[k] = xp2[k];
        }

        // ---- balanced PD + LIF + MRR power ----
        const float c0  = (se - so) * dd0;
        const float m2A = (mem0 > 0.55f) ? 0.0f : fmaf(0.95f, mem0, c0);
        mem0 = m2A;
        const float pw  = (m2A > 0.55f) ? pon : poff;

        if (isL0) {
            out[opw_i] = pw;                     // 18 consecutive dwords/group
            out[om0_i] = m2A;
        }

        // ---- broadcast 18 pw values within the 32-lane group ----
        float pwall[18];
        #define GATHER(k) pwall[k] = swzf<((k) << 5)>(pw);
        GATHER(0)  GATHER(1)  GATHER(2)  GATHER(3)  GATHER(4)  GATHER(5)
        GATHER(6)  GATHER(7)  GATHER(8)  GATHER(9)  GATHER(10) GATHER(11)
        GATHER(12) GATHER(13) GATHER(14) GATHER(15) GATHER(16) GATHER(17)
        #undef GATHER

        // ---- layer 1: this lane's column, ascending w ----
        float i1 = 0.f;
        #pragma unroll
        for (int w = 0; w < 18; ++w)
            i1 = fmaf(pwall[w], w1[w], i1);

        const float i1p = swzf<0x041F>(i1);      // partner column (xor 1)
        const float c1  = (i1 - i1p) * dd1;      // even-col - odd-col on even
        const float m2B = (mem1 > 0.25f) ? 0.0f : fmaf(0.95f, mem1, c1);
        mem1 = m2B;

        if (isOut1) {
            out[os1_i] = (m2B > 0.25f) ? 1.0f : 0.0f;
            out[om1_i] = m2B;
        }

        opw_i += Bn * 18;
        om0_i += Bn * 18;
        os1_i += Bn * 8;
        om1_i += Bn * 8;
    }
}

extern "C" void kernel_launch(void* const* d_in, const int* in_sizes, int n_in,
                              void* d_out, int out_size, void* d_ws, size_t ws_size,
                              hipStream_t stream) {
    (void)in_sizes; (void)n_in; (void)out_size; (void)d_ws; (void)ws_size;
    const float* x  = (const float*)d_in[0];
    const float* W0 = (const float*)d_in[1];
    const float* d0 = (const float*)d_in[2];
    const float* W1 = (const float*)d_in[3];
    const float* d1 = (const float*)d_in[4];
    const float* pk = (const float*)d_in[5];
    float* out = (float*)d_out;

    dim3 grid(Bn / 8), block(256);   // 32 lanes/batch, 2 batches/wave
    hipLaunchKernelGGL(oesnn_kernel, grid, block, 0, stream,
                       x, W0, d0, W1, d1, pk, out);
}